// Round 2
// baseline (502.211 us; speedup 1.0000x reference)
//
#include <hip/hip_runtime.h>
#include <stdint.h>

#define TT 2048
#define HH 1024
#define II 4096
#define EE 8
#define KS 4
#define KSPAN (II / KS)

typedef __attribute__((ext_vector_type(4))) float floatx4;
typedef __attribute__((ext_vector_type(8))) __bf16 bf16x8;

// round-to-nearest-even fp32 -> bf16 (bits)
__device__ __forceinline__ unsigned short f2bf(float f) {
  union { float f; unsigned u; } v; v.f = f;
  return (unsigned short)((v.u + 0x7FFFu + ((v.u >> 16) & 1u)) >> 16);
}

// async global->LDS, 16 bytes per lane; LDS dest must be wave-uniform base + lane*16
__device__ __forceinline__ void async_ld16(const void* g, void* l) {
  __builtin_amdgcn_global_load_lds(
      (__attribute__((address_space(1))) void*)g,
      (__attribute__((address_space(3))) void*)l, 16, 0, 0);
}

#define CFENCE asm volatile("" ::: "memory")
#define WAIT_VM0 asm volatile("s_waitcnt vmcnt(0)" ::: "memory")

// ---------------- weight conversion: fp32 -> bf16, streaming ----------------
__global__ __launch_bounds__(256) void k_convw(
    const float* __restrict__ w1, const float* __restrict__ w2,
    unsigned short* __restrict__ w1b, unsigned short* __restrict__ w2b) {
  const int N4 = EE * II * HH / 4;  // float4 chunks per weight tensor
  int idx = blockIdx.x * 256 + threadIdx.x;
  const int stride = gridDim.x * 256;
  for (int i = idx; i < 2 * N4; i += stride) {
    const float* src;
    unsigned short* dst;
    int j;
    if (i < N4) { src = w1; dst = w1b; j = i; }
    else        { src = w2; dst = w2b; j = i - N4; }
    floatx4 a = ((const floatx4*)src)[j];
    ushort4 o;
    o.x = f2bf(a.x); o.y = f2bf(a.y); o.z = f2bf(a.z); o.w = f2bf(a.w);
    ((ushort4*)dst)[j] = o;
  }
}

// ---------------- gating: fp32 logits, softmax top-2, renorm; emit x_bf16 ----
__global__ __launch_bounds__(256) void k_gating(
    const float* __restrict__ x, const float* __restrict__ gw,
    unsigned short* __restrict__ xb, int* __restrict__ sel_e,
    float* __restrict__ sel_w, int* __restrict__ counts) {
  int t = blockIdx.x;
  int tid = threadIdx.x;
  floatx4 xv = ((const floatx4*)(x + (size_t)t * HH))[tid];
  ushort4 xo;
  xo.x = f2bf(xv.x); xo.y = f2bf(xv.y); xo.z = f2bf(xv.z); xo.w = f2bf(xv.w);
  ((ushort4*)(xb + (size_t)t * HH))[tid] = xo;

  float part[EE];
#pragma unroll
  for (int e = 0; e < EE; e++) {
    floatx4 g = ((const floatx4*)(gw + e * HH))[tid];
    part[e] = xv.x * g.x + xv.y * g.y + xv.z * g.z + xv.w * g.w;
  }
#pragma unroll
  for (int e = 0; e < EE; e++) {
    float v = part[e];
#pragma unroll
    for (int off = 32; off > 0; off >>= 1) v += __shfl_down(v, off, 64);
    part[e] = v;
  }
  __shared__ float red[4][EE];
  int wave = tid >> 6;
  if ((tid & 63) == 0) {
#pragma unroll
    for (int e = 0; e < EE; e++) red[wave][e] = part[e];
  }
  __syncthreads();
  if (tid == 0) {
    float lg[EE];
#pragma unroll
    for (int e = 0; e < EE; e++)
      lg[e] = red[0][e] + red[1][e] + red[2][e] + red[3][e];
    int e0 = 0;
#pragma unroll
    for (int e = 1; e < EE; e++) if (lg[e] > lg[e0]) e0 = e;
    int e1 = (e0 == 0) ? 1 : 0;
#pragma unroll
    for (int e = 0; e < EE; e++) if (e != e0 && lg[e] > lg[e1]) e1 = e;
    float w0 = 1.f / (1.f + expf(lg[e1] - lg[e0]));
    sel_e[t * 2] = e0; sel_e[t * 2 + 1] = e1;
    sel_w[t * 2] = w0; sel_w[t * 2 + 1] = 1.f - w0;
    atomicAdd(&counts[e0], 1);
    atomicAdd(&counts[e1], 1);
  }
}

// ---------------- scan + fill (single block, LDS counters) ------------------
__global__ __launch_bounds__(256) void k_fill(
    const int* __restrict__ counts, const int* __restrict__ sel_e,
    const float* __restrict__ sel_w, int* __restrict__ bases,
    int* __restrict__ row_token, float* __restrict__ row_w,
    int* __restrict__ inv_slot) {
  __shared__ int lb[EE];
  __shared__ int lc[EE];
  int tid = threadIdx.x;
  if (tid == 0) {
    int s = 0;
    for (int e = 0; e < EE; e++) { lb[e] = s; s += counts[e]; }
  }
  if (tid < EE) lc[tid] = 0;
  __syncthreads();
  for (int p = tid; p < TT * 2; p += 256) {
    int e = sel_e[p];
    int slot = lb[e] + atomicAdd(&lc[e], 1);
    row_token[slot] = p >> 1;
    row_w[slot] = sel_w[p];
    inv_slot[p] = slot;
  }
  __syncthreads();
  if (tid < EE) bases[tid] = lb[tid];
}

// ---------------- GEMM1: hid = silu(x @ w1b^T) ------------------------------
// Pure DMA (global_load_lds x4) double-buffered loop: one barrier + one
// vmcnt(0) per K-step, zero staging VALU work. XOR-swizzled LDS (via
// pre-swizzled global source column; linear DMA dest).
__global__ __launch_bounds__(256) void k_gemm1(
    const unsigned short* __restrict__ xb,
    const unsigned short* __restrict__ w1b,
    unsigned short* __restrict__ hid,
    const int* __restrict__ counts, const int* __restrict__ bases,
    const int* __restrict__ row_token) {
  const int e = blockIdx.z;
  const int count = counts[e];
  const int m0 = blockIdx.y * 128;
  if (m0 >= count) return;
  const int n0 = blockIdx.x * 128;
  const int base = bases[e];

  __shared__ __align__(16) unsigned short Smem[4 * 4096];  // A0 A1 B0 B1 = 32 KB
  unsigned short* const A0b = Smem;
  unsigned short* const A1b = Smem + 4096;
  unsigned short* const B0b = Smem + 8192;
  unsigned short* const B1b = Smem + 12288;

  const int tid = threadIdx.x;
  const int lane = tid & 63;
  const int wave = tid >> 6;
  const int wm = (wave & 1) * 64;
  const int wn = (wave >> 1) * 64;
  const int quad = lane >> 4;
  const int l16 = lane & 15;

  const int rA0 = tid >> 2;                      // tile rows 0..63 (+64)
  const int swz = (tid & 3) ^ ((tid >> 3) & 3);  // XOR involution on 16B chunks
  const int cc = swz * 8;                        // pre-swizzled global col (bf16 elems)
  const int ldsOff = tid * 8;                    // linear DMA dest (shorts)

  int g0 = m0 + rA0;      if (g0 > count - 1) g0 = count - 1;
  int g1 = m0 + rA0 + 64; if (g1 > count - 1) g1 = count - 1;
  const unsigned short* aS0 = xb + (size_t)row_token[base + g0] * HH + cc;
  const unsigned short* aS1 = xb + (size_t)row_token[base + g1] * HH + cc;
  const unsigned short* wp = w1b + (size_t)e * II * HH;
  const unsigned short* bS0 = wp + (size_t)(n0 + rA0) * HH + cc;
  const unsigned short* bS1 = bS0 + (size_t)64 * HH;

  // swizzled fragment read offsets (shorts)
  int offA[4], offB[4];
#pragma unroll
  for (int i = 0; i < 4; i++) {
    const int Ra = wm + i * 16 + l16;
    offA[i] = Ra * 32 + 8 * (quad ^ ((Ra >> 1) & 3));
    const int Rb = wn + i * 16 + l16;
    offB[i] = Rb * 32 + 8 * (quad ^ ((Rb >> 1) & 3));
  }

  const floatx4 fz = {0.f, 0.f, 0.f, 0.f};
  floatx4 acc[4][4];
#pragma unroll
  for (int i = 0; i < 4; i++)
#pragma unroll
    for (int j = 0; j < 4; j++) acc[i][j] = fz;

  // prologue: stage tile 0
  async_ld16(aS0, A0b + ldsOff);
  async_ld16(aS1, A0b + ldsOff + 2048);
  async_ld16(bS0, B0b + ldsOff);
  async_ld16(bS1, B0b + ldsOff + 2048);
  WAIT_VM0;
  __builtin_amdgcn_s_barrier();
  CFENCE;

  unsigned short* Ac = A0b; unsigned short* An = A1b;
  unsigned short* Bc = B0b; unsigned short* Bn = B1b;

  for (int k0 = 0; k0 < HH; k0 += 32) {
    if (k0 + 32 < HH) {
      async_ld16(aS0 + k0 + 32, An + ldsOff);
      async_ld16(aS1 + k0 + 32, An + ldsOff + 2048);
      async_ld16(bS0 + k0 + 32, Bn + ldsOff);
      async_ld16(bS1 + k0 + 32, Bn + ldsOff + 2048);
    }
    CFENCE;
    bf16x8 af[4], bfr[4];
#pragma unroll
    for (int i = 0; i < 4; i++) {
      af[i]  = *(const bf16x8*)(Ac + offA[i]);
      bfr[i] = *(const bf16x8*)(Bc + offB[i]);
    }
#pragma unroll
    for (int i = 0; i < 4; i++)
#pragma unroll
      for (int j = 0; j < 4; j++)
        acc[i][j] = __builtin_amdgcn_mfma_f32_16x16x32_bf16(af[i], bfr[j], acc[i][j], 0, 0, 0);
    WAIT_VM0;                       // next-tile DMA landed (latency hidden under MFMA)
    __builtin_amdgcn_s_barrier();   // all waves done reading cur + staging next
    CFENCE;
    { unsigned short* t = Ac; Ac = An; An = t; }
    { unsigned short* t = Bc; Bc = Bn; Bn = t; }
  }

  // epilogue: silu -> bf16 -> per-wave LDS bounce -> coalesced 16B stores.
  unsigned short* Sl = Smem + wave * (16 * 72);
#pragma unroll
  for (int i = 0; i < 4; i++) {
#pragma unroll
    for (int r = 0; r < 4; r++) {
      const int row16 = quad * 4 + r;
#pragma unroll
      for (int j = 0; j < 4; j++) {
        float z = acc[i][j][r];
        Sl[row16 * 72 + l16 + 16 * j] = f2bf(z / (1.f + __expf(-z)));
      }
    }
#pragma unroll
    for (int half = 0; half < 2; half++) {
      const int row16 = (lane >> 3) + 8 * half;
      const int m = wm + i * 16 + row16;
      if (m0 + m < count) {
        bf16x8 v = *(const bf16x8*)(Sl + row16 * 72 + (lane & 7) * 8);
        *(bf16x8*)(hid + (size_t)(base + m0 + m) * II + n0 + wn + (lane & 7) * 8) = v;
      }
    }
  }
}

// ---------------- GEMM2: yp[ks][slot] = hid @ w2b^T (split-K, plain stores) -
__global__ __launch_bounds__(256) void k_gemm2(
    const unsigned short* __restrict__ hid,
    const unsigned short* __restrict__ w2b,
    float* __restrict__ yp,
    const int* __restrict__ counts, const int* __restrict__ bases) {
  const int e = blockIdx.z;
  const int count = counts[e];
  const int m0 = blockIdx.y * 128;
  if (m0 >= count) return;
  const int nt = blockIdx.x & 7;
  const int ks = blockIdx.x >> 3;
  const int n0 = nt * 128;
  const int base = bases[e];
  const int kbeg = ks * KSPAN;

  __shared__ __align__(16) unsigned short Smem2[4 * 4096];
  unsigned short* const A0b = Smem2;
  unsigned short* const A1b = Smem2 + 4096;
  unsigned short* const B0b = Smem2 + 8192;
  unsigned short* const B1b = Smem2 + 12288;

  const int tid = threadIdx.x;
  const int lane = tid & 63;
  const int wave = tid >> 6;
  const int wm = (wave & 1) * 64;
  const int wn = (wave >> 1) * 64;
  const int quad = lane >> 4;
  const int l16 = lane & 15;

  const int rA0 = tid >> 2;
  const int swz = (tid & 3) ^ ((tid >> 3) & 3);
  const int cc = swz * 8;
  const int ldsOff = tid * 8;

  int g0 = m0 + rA0;      if (g0 > count - 1) g0 = count - 1;
  int g1 = m0 + rA0 + 64; if (g1 > count - 1) g1 = count - 1;
  const unsigned short* aS0 = hid + (size_t)(base + g0) * II + kbeg + cc;
  const unsigned short* aS1 = hid + (size_t)(base + g1) * II + kbeg + cc;
  const unsigned short* wp = w2b + (size_t)e * HH * II;
  const unsigned short* bS0 = wp + (size_t)(n0 + rA0) * II + kbeg + cc;
  const unsigned short* bS1 = bS0 + (size_t)64 * II;

  int offA[4], offB[4];
#pragma unroll
  for (int i = 0; i < 4; i++) {
    const int Ra = wm + i * 16 + l16;
    offA[i] = Ra * 32 + 8 * (quad ^ ((Ra >> 1) & 3));
    const int Rb = wn + i * 16 + l16;
    offB[i] = Rb * 32 + 8 * (quad ^ ((Rb >> 1) & 3));
  }

  const floatx4 fz = {0.f, 0.f, 0.f, 0.f};
  floatx4 acc[4][4];
#pragma unroll
  for (int i = 0; i < 4; i++)
#pragma unroll
    for (int j = 0; j < 4; j++) acc[i][j] = fz;

  async_ld16(aS0, A0b + ldsOff);
  async_ld16(aS1, A0b + ldsOff + 2048);
  async_ld16(bS0, B0b + ldsOff);
  async_ld16(bS1, B0b + ldsOff + 2048);
  WAIT_VM0;
  __builtin_amdgcn_s_barrier();
  CFENCE;

  unsigned short* Ac = A0b; unsigned short* An = A1b;
  unsigned short* Bc = B0b; unsigned short* Bn = B1b;

  for (int k0 = 0; k0 < KSPAN; k0 += 32) {
    if (k0 + 32 < KSPAN) {
      async_ld16(aS0 + k0 + 32, An + ldsOff);
      async_ld16(aS1 + k0 + 32, An + ldsOff + 2048);
      async_ld16(bS0 + k0 + 32, Bn + ldsOff);
      async_ld16(bS1 + k0 + 32, Bn + ldsOff + 2048);
    }
    CFENCE;
    bf16x8 af[4], bfr[4];
#pragma unroll
    for (int i = 0; i < 4; i++) {
      af[i]  = *(const bf16x8*)(Ac + offA[i]);
      bfr[i] = *(const bf16x8*)(Bc + offB[i]);
    }
#pragma unroll
    for (int i = 0; i < 4; i++)
#pragma unroll
      for (int j = 0; j < 4; j++)
        acc[i][j] = __builtin_amdgcn_mfma_f32_16x16x32_bf16(af[i], bfr[j], acc[i][j], 0, 0, 0);
    WAIT_VM0;
    __builtin_amdgcn_s_barrier();
    CFENCE;
    { unsigned short* t = Ac; Ac = An; An = t; }
    { unsigned short* t = Bc; Bc = Bn; Bn = t; }
  }

#pragma unroll
  for (int i = 0; i < 4; i++) {
#pragma unroll
    for (int r = 0; r < 4; r++) {
      const int m = wm + i * 16 + quad * 4 + r;
      if (m0 + m < count) {
        float* op = yp + ((size_t)ks * (TT * 2) + base + m0 + m) * HH + n0 + wn + l16;
#pragma unroll
        for (int j = 0; j < 4; j++) op[j * 16] = acc[i][j][r];
      }
    }
  }
}

// ---------------- combine: out[t] = sum_k w_k * sum_ks yp[ks][slot_k] -------
__global__ __launch_bounds__(256) void k_combine(
    const float* __restrict__ yp, const int* __restrict__ inv_slot,
    const float* __restrict__ sel_w, float* __restrict__ out) {
  const int t = blockIdx.x;
  const int tid = threadIdx.x;
  const int s0 = inv_slot[2 * t];
  const int s1 = inv_slot[2 * t + 1];
  const float w0 = sel_w[2 * t];
  const float w1 = sel_w[2 * t + 1];
  floatx4 a = {0.f, 0.f, 0.f, 0.f};
  floatx4 b = {0.f, 0.f, 0.f, 0.f};
#pragma unroll
  for (int ks = 0; ks < KS; ks++) {
    a += ((const floatx4*)(yp + ((size_t)ks * (TT * 2) + s0) * HH))[tid];
    b += ((const floatx4*)(yp + ((size_t)ks * (TT * 2) + s1) * HH))[tid];
  }
  floatx4 v = w0 * a + w1 * b;
  ((floatx4*)(out + (size_t)t * HH))[tid] = v;
}

// ---------------- launch ----------------------------------------------------
extern "C" void kernel_launch(void* const* d_in, const int* in_sizes, int n_in,
                              void* d_out, int out_size, void* d_ws, size_t ws_size,
                              hipStream_t stream) {
  const float* x  = (const float*)d_in[0];
  const float* gw = (const float*)d_in[1];
  const float* w1 = (const float*)d_in[2];
  const float* w2 = (const float*)d_in[3];
  float* out = (float*)d_out;

  char* ws = (char*)d_ws;
  size_t off = 0;
  auto take = [&](size_t n) -> char* {
    char* p = ws + off;
    off += (n + 255) & ~(size_t)255;
    return p;
  };
  unsigned short* xb  = (unsigned short*)take((size_t)TT * HH * 2);
  unsigned short* hid = (unsigned short*)take((size_t)TT * 2 * II * 2);
  // w1b (67.1 MB) is dead after k_gemm1; yp (exactly 67.1 MB) aliases it.
  unsigned short* w1b = (unsigned short*)take((size_t)EE * II * HH * 2);
  float* yp = (float*)w1b;
  unsigned short* w2b = (unsigned short*)take((size_t)EE * II * HH * 2);
  int*   counts    = (int*)take(EE * 4);
  int*   bases     = (int*)take(EE * 4);
  int*   row_token = (int*)take((size_t)TT * 2 * 4);
  float* row_w     = (float*)take((size_t)TT * 2 * 4);
  int*   sel_e     = (int*)take((size_t)TT * 2 * 4);
  float* sel_w     = (float*)take((size_t)TT * 2 * 4);
  int*   inv_slot  = (int*)take((size_t)TT * 2 * 4);
  if (off > ws_size) return;  // workspace too small — fail loudly via absmax

  hipMemsetAsync(counts, 0, EE * 4, stream);

  k_convw<<<2048, 256, 0, stream>>>(w1, w2, w1b, w2b);
  k_gating<<<TT, 256, 0, stream>>>(x, gw, xb, sel_e, sel_w, counts);
  k_fill<<<1, 256, 0, stream>>>(counts, sel_e, sel_w, bases, row_token, row_w, inv_slot);
  k_gemm1<<<dim3(II / 128, 16, EE), 256, 0, stream>>>(xb, w1b, hid, counts, bases, row_token);
  k_gemm2<<<dim3(8 * KS, 16, EE), 256, 0, stream>>>(hid, w2b, yp, counts, bases);
  k_combine<<<TT, 256, 0, stream>>>(yp, inv_slot, sel_w, out);
}

// Round 3
// 477.180 us; speedup vs baseline: 1.0525x; 1.0525x over previous
//
#include <hip/hip_runtime.h>
#include <stdint.h>

#define TT 2048
#define HH 1024
#define II 4096
#define EE 8
#define KS 4
#define KSPAN (II / KS)

typedef __attribute__((ext_vector_type(4))) float floatx4;
typedef __attribute__((ext_vector_type(8))) __bf16 bf16x8;
typedef __attribute__((ext_vector_type(8))) unsigned short ushort8v;

// round-to-nearest-even fp32 -> bf16 (bits)
__device__ __forceinline__ unsigned short f2bf(float f) {
  union { float f; unsigned u; } v; v.f = f;
  return (unsigned short)((v.u + 0x7FFFu + ((v.u >> 16) & 1u)) >> 16);
}

// async global->LDS, 16 bytes per lane; LDS dest must be wave-uniform base + lane*16
__device__ __forceinline__ void async_ld16(const void* g, void* l) {
  __builtin_amdgcn_global_load_lds(
      (__attribute__((address_space(1))) void*)g,
      (__attribute__((address_space(3))) void*)l, 16, 0, 0);
}

#define CFENCE asm volatile("" ::: "memory")
#define WAIT_VM(n) asm volatile("s_waitcnt vmcnt(" #n ")" ::: "memory")

// ---------------- prep: fused gating (blocks 0..2047) + weight conversion ---
// convw part: branchless grid-stride, 32B/lane NT loads, 16B/lane stores.
__global__ __launch_bounds__(256) void k_prep(
    const float* __restrict__ x, const float* __restrict__ gw,
    const float* __restrict__ w1, const float* __restrict__ w2,
    unsigned short* __restrict__ xb, unsigned short* __restrict__ w1b,
    unsigned short* __restrict__ w2b, int* __restrict__ sel_e,
    float* __restrict__ sel_w, int* __restrict__ counts) {
  const int bid = blockIdx.x;
  const int tid = threadIdx.x;

  if (bid >= TT) {
    // ---- weight conversion: 2048 blocks per tensor, 8 chunks of 8 floats each
    const int cb = bid - TT;              // 0..4095
    const int tensor = cb >> 11;          // 0 -> w1, 1 -> w2
    const int b = cb & 2047;
    const float* src = tensor ? w2 : w1;
    unsigned short* dst = tensor ? w2b : w1b;
    const int idx = b * 256 + tid;        // < 524288
#pragma unroll
    for (int it = 0; it < 8; ++it) {
      const int c = idx + it * 524288;    // chunk of 8 floats; n8 = 4194304
      floatx4 a = __builtin_nontemporal_load((const floatx4*)src + 2 * c);
      floatx4 bb = __builtin_nontemporal_load((const floatx4*)src + 2 * c + 1);
      ushort8v o;
      o[0] = f2bf(a.x); o[1] = f2bf(a.y); o[2] = f2bf(a.z); o[3] = f2bf(a.w);
      o[4] = f2bf(bb.x); o[5] = f2bf(bb.y); o[6] = f2bf(bb.z); o[7] = f2bf(bb.w);
      ((ushort8v*)dst)[c] = o;
    }
    return;
  }

  // ---- gating for token t = bid
  const int t = bid;
  floatx4 xv = ((const floatx4*)(x + (size_t)t * HH))[tid];
  ushort4 xo;
  xo.x = f2bf(xv.x); xo.y = f2bf(xv.y); xo.z = f2bf(xv.z); xo.w = f2bf(xv.w);
  ((ushort4*)(xb + (size_t)t * HH))[tid] = xo;

  float part[EE];
#pragma unroll
  for (int e = 0; e < EE; e++) {
    floatx4 g = ((const floatx4*)(gw + e * HH))[tid];
    part[e] = xv.x * g.x + xv.y * g.y + xv.z * g.z + xv.w * g.w;
  }
#pragma unroll
  for (int e = 0; e < EE; e++) {
    float v = part[e];
#pragma unroll
    for (int off = 32; off > 0; off >>= 1) v += __shfl_down(v, off, 64);
    part[e] = v;
  }
  __shared__ float red[4][EE];
  int wave = tid >> 6;
  if ((tid & 63) == 0) {
#pragma unroll
    for (int e = 0; e < EE; e++) red[wave][e] = part[e];
  }
  __syncthreads();
  if (tid == 0) {
    float lg[EE];
#pragma unroll
    for (int e = 0; e < EE; e++)
      lg[e] = red[0][e] + red[1][e] + red[2][e] + red[3][e];
    int e0 = 0;
#pragma unroll
    for (int e = 1; e < EE; e++) if (lg[e] > lg[e0]) e0 = e;
    int e1 = (e0 == 0) ? 1 : 0;
#pragma unroll
    for (int e = 0; e < EE; e++) if (e != e0 && lg[e] > lg[e1]) e1 = e;
    float w0 = 1.f / (1.f + expf(lg[e1] - lg[e0]));
    sel_e[t * 2] = e0; sel_e[t * 2 + 1] = e1;
    sel_w[t * 2] = w0; sel_w[t * 2 + 1] = 1.f - w0;
    atomicAdd(&counts[e0], 1);
    atomicAdd(&counts[e1], 1);
  }
}

// ---------------- scan + fill (single block, LDS counters) ------------------
__global__ __launch_bounds__(256) void k_fill(
    const int* __restrict__ counts, const int* __restrict__ sel_e,
    const float* __restrict__ sel_w, int* __restrict__ bases,
    int* __restrict__ row_token, float* __restrict__ row_w,
    int* __restrict__ inv_slot) {
  __shared__ int lb[EE];
  __shared__ int lc[EE];
  int tid = threadIdx.x;
  if (tid == 0) {
    int s = 0;
    for (int e = 0; e < EE; e++) { lb[e] = s; s += counts[e]; }
  }
  if (tid < EE) lc[tid] = 0;
  __syncthreads();
  for (int p = tid; p < TT * 2; p += 256) {
    int e = sel_e[p];
    int slot = lb[e] + atomicAdd(&lc[e], 1);
    row_token[slot] = p >> 1;
    row_w[slot] = sel_w[p];
    inv_slot[p] = slot;
  }
  __syncthreads();
  if (tid < EE) bases[tid] = lb[tid];
}

// ---------------- GEMM1: hid = silu(x @ w1b^T) ------------------------------
// 3-buffer DMA pipeline, counted vmcnt(4): tile k+2 issued at step k, waited
// at step k+1 — HBM/L3 latency gets two compute windows of cover. One barrier
// per step; never drain vmcnt to 0 mid-loop. XOR-swizzled LDS.
__global__ __launch_bounds__(256) void k_gemm1(
    const unsigned short* __restrict__ xb,
    const unsigned short* __restrict__ w1b,
    unsigned short* __restrict__ hid,
    const int* __restrict__ counts, const int* __restrict__ bases,
    const int* __restrict__ row_token) {
  const int e = blockIdx.z;
  const int count = counts[e];
  const int m0 = blockIdx.y * 128;
  if (m0 >= count) return;
  const int n0 = blockIdx.x * 128;
  const int base = bases[e];

  // 3 buffers x (A 8KB + B 8KB) = 48 KB
  __shared__ __align__(16) unsigned short Smem[3 * 8192];

  const int tid = threadIdx.x;
  const int lane = tid & 63;
  const int wave = tid >> 6;
  const int wm = (wave & 1) * 64;
  const int wn = (wave >> 1) * 64;
  const int quad = lane >> 4;
  const int l16 = lane & 15;

  const int rA0 = tid >> 2;                      // tile rows 0..63 (+64)
  const int swz = (tid & 3) ^ ((tid >> 3) & 3);  // XOR involution on 16B chunks
  const int cc = swz * 8;                        // pre-swizzled global col
  const int ldsOff = tid * 8;                    // linear DMA dest (shorts)

  int g0 = m0 + rA0;      if (g0 > count - 1) g0 = count - 1;
  int g1 = m0 + rA0 + 64; if (g1 > count - 1) g1 = count - 1;
  const unsigned short* aS0 = xb + (size_t)row_token[base + g0] * HH + cc;
  const unsigned short* aS1 = xb + (size_t)row_token[base + g1] * HH + cc;
  const unsigned short* wp = w1b + (size_t)e * II * HH;
  const unsigned short* bS0 = wp + (size_t)(n0 + rA0) * HH + cc;
  const unsigned short* bS1 = bS0 + (size_t)64 * HH;

  // swizzled fragment read offsets (shorts), relative to buffer base
  int offA[4], offB[4];
#pragma unroll
  for (int i = 0; i < 4; i++) {
    const int Ra = wm + i * 16 + l16;
    offA[i] = Ra * 32 + 8 * (quad ^ ((Ra >> 1) & 3));
    const int Rb = wn + i * 16 + l16;
    offB[i] = 4096 + Rb * 32 + 8 * (quad ^ ((Rb >> 1) & 3));
  }

  const floatx4 fz = {0.f, 0.f, 0.f, 0.f};
  floatx4 acc[4][4];
#pragma unroll
  for (int i = 0; i < 4; i++)
#pragma unroll
    for (int j = 0; j < 4; j++) acc[i][j] = fz;

  unsigned short* b0 = Smem;           // compute buffer (tile k)
  unsigned short* b1 = Smem + 8192;    // landing (tile k+1)
  unsigned short* b2 = Smem + 16384;   // issue target (tile k+2)

  // prologue: issue T0 -> b0, T1 -> b1; require T0 landed (T1 in flight)
  async_ld16(aS0, b0 + ldsOff);
  async_ld16(aS1, b0 + ldsOff + 2048);
  async_ld16(bS0, b0 + 4096 + ldsOff);
  async_ld16(bS1, b0 + 4096 + ldsOff + 2048);
  async_ld16(aS0 + 32, b1 + ldsOff);
  async_ld16(aS1 + 32, b1 + ldsOff + 2048);
  async_ld16(bS0 + 32, b1 + 4096 + ldsOff);
  async_ld16(bS1 + 32, b1 + 4096 + ldsOff + 2048);
  WAIT_VM(4);
  __builtin_amdgcn_s_barrier();
  CFENCE;

  for (int k0 = 0; k0 < HH; k0 += 32) {
    const bool issue2 = (k0 + 64 < HH);
    if (issue2) {
      async_ld16(aS0 + k0 + 64, b2 + ldsOff);
      async_ld16(aS1 + k0 + 64, b2 + ldsOff + 2048);
      async_ld16(bS0 + k0 + 64, b2 + 4096 + ldsOff);
      async_ld16(bS1 + k0 + 64, b2 + 4096 + ldsOff + 2048);
    }
    CFENCE;
    bf16x8 af[4], bfr[4];
#pragma unroll
    for (int i = 0; i < 4; i++) {
      af[i]  = *(const bf16x8*)(b0 + offA[i]);
      bfr[i] = *(const bf16x8*)(b0 + offB[i]);
    }
#pragma unroll
    for (int i = 0; i < 4; i++)
#pragma unroll
      for (int j = 0; j < 4; j++)
        acc[i][j] = __builtin_amdgcn_mfma_f32_16x16x32_bf16(af[i], bfr[j], acc[i][j], 0, 0, 0);
    CFENCE;
    if (issue2) { WAIT_VM(4); } else { WAIT_VM(0); }
    __builtin_amdgcn_s_barrier();
    CFENCE;
    unsigned short* t = b0; b0 = b1; b1 = b2; b2 = t;
  }

  // epilogue: silu -> bf16 -> per-wave LDS bounce -> coalesced 16B stores.
  unsigned short* Sl = Smem + wave * (16 * 72);
#pragma unroll
  for (int i = 0; i < 4; i++) {
#pragma unroll
    for (int r = 0; r < 4; r++) {
      const int row16 = quad * 4 + r;
#pragma unroll
      for (int j = 0; j < 4; j++) {
        float z = acc[i][j][r];
        Sl[row16 * 72 + l16 + 16 * j] = f2bf(z / (1.f + __expf(-z)));
      }
    }
#pragma unroll
    for (int half = 0; half < 2; half++) {
      const int row16 = (lane >> 3) + 8 * half;
      const int m = wm + i * 16 + row16;
      if (m0 + m < count) {
        bf16x8 v = *(const bf16x8*)(Sl + row16 * 72 + (lane & 7) * 8);
        *(bf16x8*)(hid + (size_t)(base + m0 + m) * II + n0 + wn + (lane & 7) * 8) = v;
      }
    }
  }
}

// ---------------- GEMM2: yp[ks][slot] = hid @ w2b^T (split-K, plain stores) -
__global__ __launch_bounds__(256) void k_gemm2(
    const unsigned short* __restrict__ hid,
    const unsigned short* __restrict__ w2b,
    float* __restrict__ yp,
    const int* __restrict__ counts, const int* __restrict__ bases) {
  const int e = blockIdx.z;
  const int count = counts[e];
  const int m0 = blockIdx.y * 128;
  if (m0 >= count) return;
  const int nt = blockIdx.x & 7;
  const int ks = blockIdx.x >> 3;
  const int n0 = nt * 128;
  const int base = bases[e];
  const int kbeg = ks * KSPAN;

  __shared__ __align__(16) unsigned short Smem2[3 * 8192];

  const int tid = threadIdx.x;
  const int lane = tid & 63;
  const int wave = tid >> 6;
  const int wm = (wave & 1) * 64;
  const int wn = (wave >> 1) * 64;
  const int quad = lane >> 4;
  const int l16 = lane & 15;

  const int rA0 = tid >> 2;
  const int swz = (tid & 3) ^ ((tid >> 3) & 3);
  const int cc = swz * 8;
  const int ldsOff = tid * 8;

  int g0 = m0 + rA0;      if (g0 > count - 1) g0 = count - 1;
  int g1 = m0 + rA0 + 64; if (g1 > count - 1) g1 = count - 1;
  const unsigned short* aS0 = hid + (size_t)(base + g0) * II + kbeg + cc;
  const unsigned short* aS1 = hid + (size_t)(base + g1) * II + kbeg + cc;
  const unsigned short* wp = w2b + (size_t)e * HH * II;
  const unsigned short* bS0 = wp + (size_t)(n0 + rA0) * II + kbeg + cc;
  const unsigned short* bS1 = bS0 + (size_t)64 * II;

  int offA[4], offB[4];
#pragma unroll
  for (int i = 0; i < 4; i++) {
    const int Ra = wm + i * 16 + l16;
    offA[i] = Ra * 32 + 8 * (quad ^ ((Ra >> 1) & 3));
    const int Rb = wn + i * 16 + l16;
    offB[i] = 4096 + Rb * 32 + 8 * (quad ^ ((Rb >> 1) & 3));
  }

  const floatx4 fz = {0.f, 0.f, 0.f, 0.f};
  floatx4 acc[4][4];
#pragma unroll
  for (int i = 0; i < 4; i++)
#pragma unroll
    for (int j = 0; j < 4; j++) acc[i][j] = fz;

  unsigned short* b0 = Smem2;
  unsigned short* b1 = Smem2 + 8192;
  unsigned short* b2 = Smem2 + 16384;

  async_ld16(aS0, b0 + ldsOff);
  async_ld16(aS1, b0 + ldsOff + 2048);
  async_ld16(bS0, b0 + 4096 + ldsOff);
  async_ld16(bS1, b0 + 4096 + ldsOff + 2048);
  async_ld16(aS0 + 32, b1 + ldsOff);
  async_ld16(aS1 + 32, b1 + ldsOff + 2048);
  async_ld16(bS0 + 32, b1 + 4096 + ldsOff);
  async_ld16(bS1 + 32, b1 + 4096 + ldsOff + 2048);
  WAIT_VM(4);
  __builtin_amdgcn_s_barrier();
  CFENCE;

  for (int k0 = 0; k0 < KSPAN; k0 += 32) {
    const bool issue2 = (k0 + 64 < KSPAN);
    if (issue2) {
      async_ld16(aS0 + k0 + 64, b2 + ldsOff);
      async_ld16(aS1 + k0 + 64, b2 + ldsOff + 2048);
      async_ld16(bS0 + k0 + 64, b2 + 4096 + ldsOff);
      async_ld16(bS1 + k0 + 64, b2 + 4096 + ldsOff + 2048);
    }
    CFENCE;
    bf16x8 af[4], bfr[4];
#pragma unroll
    for (int i = 0; i < 4; i++) {
      af[i]  = *(const bf16x8*)(b0 + offA[i]);
      bfr[i] = *(const bf16x8*)(b0 + offB[i]);
    }
#pragma unroll
    for (int i = 0; i < 4; i++)
#pragma unroll
      for (int j = 0; j < 4; j++)
        acc[i][j] = __builtin_amdgcn_mfma_f32_16x16x32_bf16(af[i], bfr[j], acc[i][j], 0, 0, 0);
    CFENCE;
    if (issue2) { WAIT_VM(4); } else { WAIT_VM(0); }
    __builtin_amdgcn_s_barrier();
    CFENCE;
    unsigned short* t = b0; b0 = b1; b1 = b2; b2 = t;
  }

#pragma unroll
  for (int i = 0; i < 4; i++) {
#pragma unroll
    for (int r = 0; r < 4; r++) {
      const int m = wm + i * 16 + quad * 4 + r;
      if (m0 + m < count) {
        float* op = yp + ((size_t)ks * (TT * 2) + base + m0 + m) * HH + n0 + wn + l16;
#pragma unroll
        for (int j = 0; j < 4; j++) op[j * 16] = acc[i][j][r];
      }
    }
  }
}

// ---------------- combine: out[t] = sum_k w_k * sum_ks yp[ks][slot_k] -------
__global__ __launch_bounds__(256) void k_combine(
    const float* __restrict__ yp, const int* __restrict__ inv_slot,
    const float* __restrict__ sel_w, float* __restrict__ out) {
  const int t = blockIdx.x;
  const int tid = threadIdx.x;
  const int s0 = inv_slot[2 * t];
  const int s1 = inv_slot[2 * t + 1];
  const float w0 = sel_w[2 * t];
  const float w1 = sel_w[2 * t + 1];
  floatx4 a = {0.f, 0.f, 0.f, 0.f};
  floatx4 b = {0.f, 0.f, 0.f, 0.f};
#pragma unroll
  for (int ks = 0; ks < KS; ks++) {
    a += ((const floatx4*)(yp + ((size_t)ks * (TT * 2) + s0) * HH))[tid];
    b += ((const floatx4*)(yp + ((size_t)ks * (TT * 2) + s1) * HH))[tid];
  }
  floatx4 v = w0 * a + w1 * b;
  ((floatx4*)(out + (size_t)t * HH))[tid] = v;
}

// ---------------- launch ----------------------------------------------------
extern "C" void kernel_launch(void* const* d_in, const int* in_sizes, int n_in,
                              void* d_out, int out_size, void* d_ws, size_t ws_size,
                              hipStream_t stream) {
  const float* x  = (const float*)d_in[0];
  const float* gw = (const float*)d_in[1];
  const float* w1 = (const float*)d_in[2];
  const float* w2 = (const float*)d_in[3];
  float* out = (float*)d_out;

  char* ws = (char*)d_ws;
  size_t off = 0;
  auto take = [&](size_t n) -> char* {
    char* p = ws + off;
    off += (n + 255) & ~(size_t)255;
    return p;
  };
  unsigned short* xb  = (unsigned short*)take((size_t)TT * HH * 2);
  unsigned short* hid = (unsigned short*)take((size_t)TT * 2 * II * 2);
  // w1b (67.1 MB) is dead after k_gemm1; yp (exactly 67.1 MB) aliases it.
  unsigned short* w1b = (unsigned short*)take((size_t)EE * II * HH * 2);
  float* yp = (float*)w1b;
  unsigned short* w2b = (unsigned short*)take((size_t)EE * II * HH * 2);
  int*   counts    = (int*)take(EE * 4);
  int*   bases     = (int*)take(EE * 4);
  int*   row_token = (int*)take((size_t)TT * 2 * 4);
  float* row_w     = (float*)take((size_t)TT * 2 * 4);
  int*   sel_e     = (int*)take((size_t)TT * 2 * 4);
  float* sel_w     = (float*)take((size_t)TT * 2 * 4);
  int*   inv_slot  = (int*)take((size_t)TT * 2 * 4);
  if (off > ws_size) return;  // workspace too small — fail loudly via absmax

  hipMemsetAsync(counts, 0, EE * 4, stream);

  k_prep<<<TT + 4096, 256, 0, stream>>>(x, gw, w1, w2, xb, w1b, w2b, sel_e, sel_w, counts);
  k_fill<<<1, 256, 0, stream>>>(counts, sel_e, sel_w, bases, row_token, row_w, inv_slot);
  k_gemm1<<<dim3(II / 128, 16, EE), 256, 0, stream>>>(xb, w1b, hid, counts, bases, row_token);
  k_gemm2<<<dim3(8 * KS, 16, EE), 256, 0, stream>>>(hid, w2b, yp, counts, bases);
  k_combine<<<TT, 256, 0, stream>>>(yp, inv_slot, sel_w, out);
}